// Round 12
// baseline (95.657 us; speedup 1.0000x reference)
//
#include <hip/hip_runtime.h>
#include <hip/hip_bf16.h>
#include <math.h>

#define B_SZ 16384
#define DENSE 64
#define N_OH 8
#define N_MH 4
#define VOCAB 100000
#define EMB 32
#define HIST 20
#define IN_DIM 448
#define HID1 1024
#define HID2 512
#define HID3 256
#define CROSS_ORDER 4

typedef __bf16 bf16_t;
typedef __bf16 bf16x8 __attribute__((ext_vector_type(8)));
typedef __bf16 bf16x4 __attribute__((ext_vector_type(4)));
typedef float f32x16 __attribute__((ext_vector_type(16)));
typedef __attribute__((address_space(1))) const void cgvoid;
typedef __attribute__((address_space(3))) void lvoid;

// transpose tiles: W1 448x1024 -> 7x16=112, W2 1024x512 -> 16x8=128, W3 512x256 -> 8x4=32
#define TRT_BLOCKS 272
#define EMB_BLOCKS (B_SZ / 4)

// ---- fused kernel. Blocks [0,272): coalesced LDS-tiled weight transpose.
// Blocks [272, 272+4096): embed gather -> cross -> partial head dot.
__global__ __launch_bounds__(256) void embed_cross_transpose_kernel(
    const float* __restrict__ dense, const int* __restrict__ oh_idx,
    const int* __restrict__ mh_idx, const float* __restrict__ oh_emb,
    const float* __restrict__ mh_emb, const float* __restrict__ cw,
    const float* __restrict__ cb, const float* __restrict__ lw,
    const float* __restrict__ W1, const float* __restrict__ W2,
    const float* __restrict__ W3, bf16_t* __restrict__ T1,
    bf16_t* __restrict__ T2, bf16_t* __restrict__ T3,
    bf16_t* __restrict__ x0b, float* __restrict__ partial) {
  __shared__ float ldsAll[4 * IN_DIM];   // 7 KB (embed path)
  __shared__ float tile[64][65];         // 16.25 KB (transpose path)
  int bid = blockIdx.x;
  if (bid < TRT_BLOCKS) {
    const float* W; bf16_t* T; int K, N, b = bid;
    if (b < 112)      { W = W1; T = T1; K = IN_DIM; N = HID1; }
    else if (b < 240) { b -= 112; W = W2; T = T2; K = HID1; N = HID2; }
    else              { b -= 240; W = W3; T = T3; K = HID2; N = HID3; }
    int tk = b / (N / 64), tn = b % (N / 64);
    int tt = threadIdx.x;
    int rr = tt >> 4;            // 0..15
    int c4 = (tt & 15) * 4;      // 0..60
#pragma unroll
    for (int p = 0; p < 4; ++p) {
      int k = tk * 64 + p * 16 + rr;
      float4 v = *reinterpret_cast<const float4*>(&W[(size_t)k * N + tn * 64 + c4]);
      tile[p * 16 + rr][c4 + 0] = v.x;
      tile[p * 16 + rr][c4 + 1] = v.y;
      tile[p * 16 + rr][c4 + 2] = v.z;
      tile[p * 16 + rr][c4 + 3] = v.w;
    }
    __syncthreads();
#pragma unroll
    for (int p = 0; p < 4; ++p) {
      int n = p * 16 + rr;
      bf16x4 o;
      o[0] = (bf16_t)tile[c4 + 0][n];
      o[1] = (bf16_t)tile[c4 + 1][n];
      o[2] = (bf16_t)tile[c4 + 2][n];
      o[3] = (bf16_t)tile[c4 + 3][n];
      *reinterpret_cast<bf16x4*>(&T[(size_t)(tn * 64 + n) * K + tk * 64 + c4]) = o;
    }
    return;
  }
  // ---- embed + cross path (one wave per row) ----
  int wv = threadIdx.x >> 6;
  int lane = threadIdx.x & 63;
  int row = (bid - TRT_BLOCKS) * 4 + wv;
  float* L = ldsAll + wv * IN_DIM;  // [0:64)=dense [64:320)=oh [320:448)=mh

  L[lane] = dense[(size_t)row * DENSE + lane];

  {
    int f = lane >> 3, d4 = (lane & 7) * 4;
    int idx = oh_idx[row * N_OH + f];
    float4 ov = *reinterpret_cast<const float4*>(
        &oh_emb[((size_t)f * VOCAB + idx) * EMB + d4]);
    *reinterpret_cast<float4*>(&L[64 + lane * 4]) = ov;
  }

  {
    int f = lane >> 4, sub = lane & 15;
    int par = sub >> 3, d4 = (sub & 7) * 4;
    const int* hist = mh_idx + ((size_t)row * N_MH + f) * HIST;
    float4 ms = make_float4(0.f, 0.f, 0.f, 0.f);
#pragma unroll
    for (int jj = 0; jj < 10; ++jj) {
      int idx = hist[jj * 2 + par];
      float4 v = *reinterpret_cast<const float4*>(
          &mh_emb[((size_t)f * VOCAB + idx) * EMB + d4]);
      ms.x += v.x; ms.y += v.y; ms.z += v.z; ms.w += v.w;
    }
    ms.x += __shfl_xor(ms.x, 8);
    ms.y += __shfl_xor(ms.y, 8);
    ms.z += __shfl_xor(ms.z, 8);
    ms.w += __shfl_xor(ms.w, 8);
    if (par == 0)
      *reinterpret_cast<float4*>(&L[320 + f * 32 + (sub & 7) * 4]) = ms;
  }

  if (lane < 56) {
    float4 a = *reinterpret_cast<float4*>(&L[lane * 8]);
    float4 b = *reinterpret_cast<float4*>(&L[lane * 8 + 4]);
    bf16x8 o;
    o[0] = (bf16_t)a.x; o[1] = (bf16_t)a.y; o[2] = (bf16_t)a.z; o[3] = (bf16_t)a.w;
    o[4] = (bf16_t)b.x; o[5] = (bf16_t)b.y; o[6] = (bf16_t)b.z; o[7] = (bf16_t)b.w;
    *reinterpret_cast<bf16x8*>(x0b + (size_t)row * IN_DIM + lane * 8) = o;
  }

  float x0v[7], xiv[7];
#pragma unroll
  for (int r = 0; r < 7; ++r) {
    x0v[r] = L[lane + r * 64];
    xiv[r] = x0v[r];
  }
  for (int l = 0; l < CROSS_ORDER; ++l) {
    const float* w = cw + l * IN_DIM;
    const float* b = cb + l * IN_DIM;
    float dot = 0.f;
#pragma unroll
    for (int r = 0; r < 7; ++r) dot += xiv[r] * w[lane + r * 64];
#pragma unroll
    for (int s = 32; s > 0; s >>= 1) dot += __shfl_xor(dot, s);
#pragma unroll
    for (int r = 0; r < 7; ++r) xiv[r] = x0v[r] * dot + b[lane + r * 64] + xiv[r];
  }

  float s = 0.f;
#pragma unroll
  for (int r = 0; r < 7; ++r) s += xiv[r] * lw[lane + r * 64];
#pragma unroll
  for (int t = 32; t > 0; t >>= 1) s += __shfl_xor(s, t);
  if (lane == 0) partial[row] = s;
}

// ---- GEMM1: 256x256 tile, BK=64, 512 threads (8 waves 2Mx4N), 2-slot dbuf,
// counted vmcnt + kh-phase split (4 phases/tile: ds burst | barrier | setprio MFMA).
template <int N, int K, int GX>
__global__ __launch_bounds__(512) void gemm_256_db_kernel(
    const bf16_t* __restrict__ A, const bf16_t* __restrict__ Bt,
    const float* __restrict__ bias, bf16_t* __restrict__ C) {
  __shared__ bf16_t As[2][256 * 64];   // 2 x 32 KB
  __shared__ bf16_t Bs[2][256 * 64];   // 2 x 32 KB  -> 128 KB total
  const int tid = threadIdx.x;
  const int lane = tid & 63;
  const int wm = (tid >> 6) >> 2;      // 0..1  (M half)
  const int wn = (tid >> 6) & 3;       // 0..3  (N quarter)
  const int nwg = gridDim.x;
  const int bid = blockIdx.x;
  const int swz = (bid & 7) * (nwg >> 3) + (bid >> 3);
  const int row0 = (swz / GX) * 256;
  const int col0 = (swz % GX) * 256;
  constexpr size_t Kb = (size_t)K * 2;
  constexpr int NT = K / 64;           // 7 for K=448

  const int l31 = lane & 31;
  const int lh = lane >> 5;
  const int strow = tid >> 3;          // 0..63
  const int stkb0 = (tid & 7) * 16;

  f32x16 acc[4][2];
#pragma unroll
  for (int m = 0; m < 4; ++m)
#pragma unroll
    for (int n = 0; n < 2; ++n)
#pragma unroll
      for (int r = 0; r < 16; ++r) acc[m][n][r] = 0.f;

  auto STAGE = [&](int slot, int t) {
#pragma unroll
    for (int c = 0; c < 4; ++c) {
      int trow = c * 64 + strow;
      int skb = stkb0 ^ ((trow & 7) << 4);   // pre-swizzled source (rule #21)
      const char* gA = (const char*)A + (size_t)(row0 + trow) * Kb + (size_t)t * 128 + skb;
      const char* gB = (const char*)Bt + (size_t)(col0 + trow) * Kb + (size_t)t * 128 + skb;
      __builtin_amdgcn_global_load_lds((cgvoid*)gA,
          (lvoid*)((char*)As + slot * 32768 + c * 8192 + tid * 16), 16, 0, 0);
      __builtin_amdgcn_global_load_lds((cgvoid*)gB,
          (lvoid*)((char*)Bs + slot * 32768 + c * 8192 + tid * 16), 16, 0, 0);
    }
  };

  STAGE(0, 0);
  for (int t = 0; t < NT; ++t) {
    const int s = t & 1;
    if (t + 1 < NT) {
      STAGE(1 - s, t + 1);
      asm volatile("s_waitcnt vmcnt(8)" ::: "memory");  // in-order: tile t fully landed
    } else {
      asm volatile("s_waitcnt vmcnt(0)" ::: "memory");
    }
    __builtin_amdgcn_s_barrier();   // all waves' tile-t loads visible
    const char* AsS = (const char*)As + s * 32768;
    const char* BsS = (const char*)Bs + s * 32768;
#pragma unroll
    for (int kh = 0; kh < 4; ++kh) {   // phase = one kh slab
      const int koff = kh * 32 + lh * 16;
      bf16x8 a[4], b[2];
#pragma unroll
      for (int m = 0; m < 4; ++m) {
        int r = wm * 128 + m * 32 + l31;
        a[m] = *reinterpret_cast<const bf16x8*>(AsS + r * 128 + (koff ^ ((r & 7) << 4)));
      }
#pragma unroll
      for (int n = 0; n < 2; ++n) {
        int cc = wn * 64 + n * 32 + l31;
        b[n] = *reinterpret_cast<const bf16x8*>(BsS + cc * 128 + (koff ^ ((cc & 7) << 4)));
      }
      __builtin_amdgcn_s_barrier();   // phase align: group ds bursts vs MFMA bursts
      __builtin_amdgcn_s_setprio(1);
#pragma unroll
      for (int m = 0; m < 4; ++m)
#pragma unroll
        for (int n = 0; n < 2; ++n)
          acc[m][n] = __builtin_amdgcn_mfma_f32_32x32x16_bf16(a[m], b[n], acc[m][n], 0, 0, 0);
      __builtin_amdgcn_s_setprio(0);
    }
    __builtin_amdgcn_s_barrier();   // slot-s reads done -> overwrite allowed
  }

  // epilogue: 32x32 C/D layout col=lane&31, row=(reg&3)+8*(reg>>2)+4*(lane>>5)
#pragma unroll
  for (int n = 0; n < 2; ++n) {
    int col = col0 + wn * 64 + n * 32 + l31;
    float bv = bias[col];
#pragma unroll
    for (int m = 0; m < 4; ++m) {
#pragma unroll
      for (int r = 0; r < 16; ++r) {
        int row = row0 + wm * 128 + m * 32 + (r & 3) + 8 * (r >> 2) + 4 * lh;
        float v = fmaxf(acc[m][n][r] + bv, 0.f);
        C[(size_t)row * N + col] = (bf16_t)v;
      }
    }
  }
}

// ---- GEMM2: 128x128 tile, BK=64, dbuf + counted vmcnt + kh-phase split ----
template <int N, int K, int GX>
__global__ __launch_bounds__(256) void gemm_128_db_kernel(
    const bf16_t* __restrict__ A, const bf16_t* __restrict__ Bt,
    const float* __restrict__ bias, bf16_t* __restrict__ C) {
  __shared__ bf16_t As[2][128 * 64];   // 2 x 16 KB
  __shared__ bf16_t Bs[2][128 * 64];   // 2 x 16 KB -> 64 KB total
  const int tid = threadIdx.x;
  const int lane = tid & 63;
  const int wid = tid >> 6;
  const int wr = wid >> 1;
  const int wc = wid & 1;

  const int nwg = gridDim.x;
  const int bid = blockIdx.x;
  const int swz = (bid & 7) * (nwg >> 3) + (bid >> 3);
  const int row0 = (swz / GX) * 128;
  const int col0 = (swz % GX) * 128;
  constexpr size_t Kb = (size_t)K * 2;
  constexpr int NT = K / 64;           // 16 for K=1024

  const int l31 = lane & 31;
  const int lh = lane >> 5;
  const int strow = tid >> 3;
  const int stkb0 = (tid * 16) & 127;

  f32x16 acc[2][2];
#pragma unroll
  for (int m = 0; m < 2; ++m)
#pragma unroll
    for (int n = 0; n < 2; ++n)
#pragma unroll
      for (int r = 0; r < 16; ++r) acc[m][n][r] = 0.f;

  auto STAGE = [&](int slot, int t) {
#pragma unroll
    for (int c = 0; c < 4; ++c) {
      int trow = c * 32 + strow;
      int skb = stkb0 ^ ((trow & 7) << 4);
      const char* gA = (const char*)A + (size_t)(row0 + trow) * Kb + (size_t)t * 128 + skb;
      const char* gB = (const char*)Bt + (size_t)(col0 + trow) * Kb + (size_t)t * 128 + skb;
      __builtin_amdgcn_global_load_lds((cgvoid*)gA,
          (lvoid*)((char*)As + slot * 16384 + c * 4096 + wid * 1024), 16, 0, 0);
      __builtin_amdgcn_global_load_lds((cgvoid*)gB,
          (lvoid*)((char*)Bs + slot * 16384 + c * 4096 + wid * 1024), 16, 0, 0);
    }
  };

  STAGE(0, 0);
  for (int t = 0; t < NT; ++t) {
    const int s = t & 1;
    if (t + 1 < NT) {
      STAGE(1 - s, t + 1);
      asm volatile("s_waitcnt vmcnt(8)" ::: "memory");
    } else {
      asm volatile("s_waitcnt vmcnt(0)" ::: "memory");
    }
    __builtin_amdgcn_s_barrier();
    const char* AsS = (const char*)As + s * 16384;
    const char* BsS = (const char*)Bs + s * 16384;
#pragma unroll
    for (int kh = 0; kh < 4; ++kh) {
      const int koff = kh * 32 + lh * 16;
      bf16x8 a[2], b[2];
#pragma unroll
      for (int m = 0; m < 2; ++m) {
        int r = wr * 64 + m * 32 + l31;
        a[m] = *reinterpret_cast<const bf16x8*>(AsS + r * 128 + (koff ^ ((r & 7) << 4)));
      }
#pragma unroll
      for (int n = 0; n < 2; ++n) {
        int ccol = wc * 64 + n * 32 + l31;
        b[n] = *reinterpret_cast<const bf16x8*>(BsS + ccol * 128 + (koff ^ ((ccol & 7) << 4)));
      }
      __builtin_amdgcn_s_barrier();
      __builtin_amdgcn_s_setprio(1);
#pragma unroll
      for (int m = 0; m < 2; ++m)
#pragma unroll
        for (int n = 0; n < 2; ++n)
          acc[m][n] = __builtin_amdgcn_mfma_f32_32x32x16_bf16(a[m], b[n], acc[m][n], 0, 0, 0);
      __builtin_amdgcn_s_setprio(0);
    }
    __builtin_amdgcn_s_barrier();
  }

#pragma unroll
  for (int n = 0; n < 2; ++n) {
    int col = col0 + wc * 64 + n * 32 + l31;
    float bv = bias[col];
#pragma unroll
    for (int m = 0; m < 2; ++m) {
#pragma unroll
      for (int r = 0; r < 16; ++r) {
        int row = row0 + wr * 64 + m * 32 + (r & 3) + 8 * (r >> 2) + 4 * lh;
        float v = fmaxf(acc[m][n][r] + bv, 0.f);
        C[(size_t)row * N + col] = (bf16_t)v;
      }
    }
  }
}

// ---- fused GEMM3 + head: dbuf + counted vmcnt + kh-phase split ----
__global__ __launch_bounds__(256) void gemm3_final_kernel(
    const bf16_t* __restrict__ A,      // h2b [B][512]
    const bf16_t* __restrict__ Bt,     // wT3 [256][512]
    const float* __restrict__ bias,    // b3
    const float* __restrict__ lw,      // lin_w [704]
    const float* __restrict__ lb,      // lin_b
    const float* __restrict__ partial, // [B]
    float* __restrict__ out) {
  constexpr int K = HID2;  // 512
  __shared__ bf16_t As[2][64 * 64];     // 2 x 8 KB
  __shared__ bf16_t Bs[2][256 * 64];    // 2 x 32 KB -> 80 KB total
  __shared__ float rowsum[64][2];
  const int tid = threadIdx.x;
  const int lane = tid & 63;
  const int wid = tid >> 6;
  const int wr = wid >> 1;
  const int wc = wid & 1;
  const int nwg = gridDim.x;
  const int bid = blockIdx.x;
  const int swz = (bid & 7) * (nwg >> 3) + (bid >> 3);
  const int row0 = swz * 64;
  constexpr size_t Kb = (size_t)K * 2;
  constexpr int NT = K / 64;            // 8

  const int l31 = lane & 31;
  const int lh = lane >> 5;
  const int strow = tid >> 3;
  const int stkb0 = (tid * 16) & 127;

  f32x16 acc[4];
#pragma unroll
  for (int n = 0; n < 4; ++n)
#pragma unroll
    for (int r = 0; r < 16; ++r) acc[n][r] = 0.f;

  auto STAGE = [&](int slot, int t) {
#pragma unroll
    for (int c = 0; c < 2; ++c) {
      int trow = c * 32 + strow;
      int skb = stkb0 ^ ((trow & 7) << 4);
      const char* gA = (const char*)A + (size_t)(row0 + trow) * Kb + (size_t)t * 128 + skb;
      __builtin_amdgcn_global_load_lds((cgvoid*)gA,
          (lvoid*)((char*)As + slot * 8192 + c * 4096 + wid * 1024), 16, 0, 0);
    }
#pragma unroll
    for (int c = 0; c < 8; ++c) {
      int trow = c * 32 + strow;
      int skb = stkb0 ^ ((trow & 7) << 4);
      const char* gB = (const char*)Bt + (size_t)trow * Kb + (size_t)t * 128 + skb;
      __builtin_amdgcn_global_load_lds((cgvoid*)gB,
          (lvoid*)((char*)Bs + slot * 32768 + c * 4096 + wid * 1024), 16, 0, 0);
    }
  };

  STAGE(0, 0);
  for (int t = 0; t < NT; ++t) {
    const int s = t & 1;
    if (t + 1 < NT) {
      STAGE(1 - s, t + 1);
      asm volatile("s_waitcnt vmcnt(10)" ::: "memory");
    } else {
      asm volatile("s_waitcnt vmcnt(0)" ::: "memory");
    }
    __builtin_amdgcn_s_barrier();
    const char* AsS = (const char*)As + s * 8192;
    const char* BsS = (const char*)Bs + s * 32768;
#pragma unroll
    for (int kh = 0; kh < 4; ++kh) {
      const int koff = kh * 32 + lh * 16;
      int ar = wr * 32 + l31;
      bf16x8 a = *reinterpret_cast<const bf16x8*>(
          AsS + ar * 128 + (koff ^ ((ar & 7) << 4)));
      bf16x8 b[4];
#pragma unroll
      for (int n = 0; n < 4; ++n) {
        int bc = wc * 128 + n * 32 + l31;
        b[n] = *reinterpret_cast<const bf16x8*>(
            BsS + bc * 128 + (koff ^ ((bc & 7) << 4)));
      }
      __builtin_amdgcn_s_barrier();
      __builtin_amdgcn_s_setprio(1);
#pragma unroll
      for (int n = 0; n < 4; ++n)
        acc[n] = __builtin_amdgcn_mfma_f32_32x32x16_bf16(a, b[n], acc[n], 0, 0, 0);
      __builtin_amdgcn_s_setprio(0);
    }
    __builtin_amdgcn_s_barrier();
  }

  // head epilogue
  float bv[4], wv[4];
#pragma unroll
  for (int n = 0; n < 4; ++n) {
    int col = wc * 128 + n * 32 + l31;
    bv[n] = bias[col];
    wv[n] = lw[IN_DIM + col];
  }
#pragma unroll
  for (int r = 0; r < 16; ++r) {
    float v = 0.f;
#pragma unroll
    for (int n = 0; n < 4; ++n) {
      float h = fmaxf(acc[n][r] + bv[n], 0.f);
      v += h * wv[n];
    }
#pragma unroll
    for (int t = 16; t > 0; t >>= 1) v += __shfl_xor(v, t);
    if (l31 == 0)
      rowsum[wr * 32 + (r & 3) + 8 * (r >> 2) + 4 * lh][wc] = v;
  }
  __syncthreads();
  if (tid < 64) {
    int grow = row0 + tid;
    float s = rowsum[tid][0] + rowsum[tid][1] + partial[grow] + lb[0];
    out[grow] = 1.f / (1.f + expf(-s));
  }
}

extern "C" void kernel_launch(void* const* d_in, const int* in_sizes, int n_in,
                              void* d_out, int out_size, void* d_ws, size_t ws_size,
                              hipStream_t stream) {
  const float* dense = (const float*)d_in[0];
  const int* oh_idx = (const int*)d_in[1];
  const int* mh_idx = (const int*)d_in[2];
  const float* oh_emb = (const float*)d_in[3];
  const float* mh_emb = (const float*)d_in[4];
  const float* cw = (const float*)d_in[5];
  const float* cb = (const float*)d_in[6];
  const float* W1 = (const float*)d_in[7];
  const float* b1 = (const float*)d_in[8];
  const float* W2 = (const float*)d_in[9];
  const float* b2 = (const float*)d_in[10];
  const float* W3 = (const float*)d_in[11];
  const float* b3 = (const float*)d_in[12];
  const float* lw = (const float*)d_in[13];
  const float* lb = (const float*)d_in[14];
  float* out = (float*)d_out;

  // workspace layout (~68 MB)
  char* p = (char*)d_ws;
  bf16_t* x0b = (bf16_t*)p;  p += (size_t)B_SZ * IN_DIM * 2;
  bf16_t* h1b = (bf16_t*)p;  p += (size_t)B_SZ * HID1 * 2;
  bf16_t* h2b = (bf16_t*)p;  p += (size_t)B_SZ * HID2 * 2;
  bf16_t* wT1 = (bf16_t*)p;  p += (size_t)HID1 * IN_DIM * 2;
  bf16_t* wT2 = (bf16_t*)p;  p += (size_t)HID2 * HID1 * 2;
  bf16_t* wT3 = (bf16_t*)p;  p += (size_t)HID2 * HID3 * 2;
  float* partial = (float*)p; p += (size_t)B_SZ * 4;

  embed_cross_transpose_kernel<<<TRT_BLOCKS + EMB_BLOCKS, 256, 0, stream>>>(
      dense, oh_idx, mh_idx, oh_emb, mh_emb, cw, cb, lw,
      W1, W2, W3, wT1, wT2, wT3, x0b, partial);

  // G1: 256^2 dbuf + phase split, 256 blocks (1/CU)
  gemm_256_db_kernel<HID1, IN_DIM, HID1 / 256>
      <<<(B_SZ / 256) * (HID1 / 256), 512, 0, stream>>>(x0b, wT1, b1, h1b);
  // G2: 128^2 dbuf + phase split, 512 blocks (2/CU)
  gemm_128_db_kernel<HID2, HID1, HID2 / 128>
      <<<(B_SZ / 128) * (HID2 / 128), 256, 0, stream>>>(h1b, wT2, b2, h2b);

  gemm3_final_kernel<<<B_SZ / 64, 256, 0, stream>>>(
      h2b, wT3, b3, lw, lb, partial, out);
}

// Round 13
// 93.746 us; speedup vs baseline: 1.0204x; 1.0204x over previous
//
#include <hip/hip_runtime.h>
#include <hip/hip_bf16.h>
#include <math.h>

#define B_SZ 16384
#define DENSE 64
#define N_OH 8
#define N_MH 4
#define VOCAB 100000
#define EMB 32
#define HIST 20
#define IN_DIM 448
#define HID1 1024
#define HID2 512
#define HID3 256
#define CROSS_ORDER 4

typedef __bf16 bf16_t;
typedef __bf16 bf16x8 __attribute__((ext_vector_type(8)));
typedef __bf16 bf16x4 __attribute__((ext_vector_type(4)));
typedef float f32x16 __attribute__((ext_vector_type(16)));
typedef __attribute__((address_space(1))) const void cgvoid;
typedef __attribute__((address_space(3))) void lvoid;

// transpose tiles: W1 448x1024 -> 7x16=112, W2 1024x512 -> 16x8=128, W3 512x256 -> 8x4=32
#define TRT_BLOCKS 272
#define EMB_BLOCKS (B_SZ / 4)

// ---- fused kernel. Blocks [0,272): coalesced LDS-tiled weight transpose.
// Blocks [272, 272+4096): embed gather -> cross -> partial head dot.
__global__ __launch_bounds__(256) void embed_cross_transpose_kernel(
    const float* __restrict__ dense, const int* __restrict__ oh_idx,
    const int* __restrict__ mh_idx, const float* __restrict__ oh_emb,
    const float* __restrict__ mh_emb, const float* __restrict__ cw,
    const float* __restrict__ cb, const float* __restrict__ lw,
    const float* __restrict__ W1, const float* __restrict__ W2,
    const float* __restrict__ W3, bf16_t* __restrict__ T1,
    bf16_t* __restrict__ T2, bf16_t* __restrict__ T3,
    bf16_t* __restrict__ x0b, float* __restrict__ partial) {
  __shared__ float ldsAll[4 * IN_DIM];   // 7 KB (embed path)
  __shared__ float tile[64][65];         // 16.25 KB (transpose path)
  int bid = blockIdx.x;
  if (bid < TRT_BLOCKS) {
    const float* W; bf16_t* T; int K, N, b = bid;
    if (b < 112)      { W = W1; T = T1; K = IN_DIM; N = HID1; }
    else if (b < 240) { b -= 112; W = W2; T = T2; K = HID1; N = HID2; }
    else              { b -= 240; W = W3; T = T3; K = HID2; N = HID3; }
    int tk = b / (N / 64), tn = b % (N / 64);
    int tt = threadIdx.x;
    int rr = tt >> 4;            // 0..15
    int c4 = (tt & 15) * 4;      // 0..60
#pragma unroll
    for (int p = 0; p < 4; ++p) {
      int k = tk * 64 + p * 16 + rr;
      float4 v = *reinterpret_cast<const float4*>(&W[(size_t)k * N + tn * 64 + c4]);
      tile[p * 16 + rr][c4 + 0] = v.x;
      tile[p * 16 + rr][c4 + 1] = v.y;
      tile[p * 16 + rr][c4 + 2] = v.z;
      tile[p * 16 + rr][c4 + 3] = v.w;
    }
    __syncthreads();
#pragma unroll
    for (int p = 0; p < 4; ++p) {
      int n = p * 16 + rr;
      bf16x4 o;
      o[0] = (bf16_t)tile[c4 + 0][n];
      o[1] = (bf16_t)tile[c4 + 1][n];
      o[2] = (bf16_t)tile[c4 + 2][n];
      o[3] = (bf16_t)tile[c4 + 3][n];
      *reinterpret_cast<bf16x4*>(&T[(size_t)(tn * 64 + n) * K + tk * 64 + c4]) = o;
    }
    return;
  }
  // ---- embed + cross path (one wave per row) ----
  int wv = threadIdx.x >> 6;
  int lane = threadIdx.x & 63;
  int row = (bid - TRT_BLOCKS) * 4 + wv;
  float* L = ldsAll + wv * IN_DIM;  // [0:64)=dense [64:320)=oh [320:448)=mh

  L[lane] = dense[(size_t)row * DENSE + lane];

  {
    int f = lane >> 3, d4 = (lane & 7) * 4;
    int idx = oh_idx[row * N_OH + f];
    float4 ov = *reinterpret_cast<const float4*>(
        &oh_emb[((size_t)f * VOCAB + idx) * EMB + d4]);
    *reinterpret_cast<float4*>(&L[64 + lane * 4]) = ov;
  }

  {
    int f = lane >> 4, sub = lane & 15;
    int par = sub >> 3, d4 = (sub & 7) * 4;
    const int* hist = mh_idx + ((size_t)row * N_MH + f) * HIST;
    float4 ms = make_float4(0.f, 0.f, 0.f, 0.f);
#pragma unroll
    for (int jj = 0; jj < 10; ++jj) {
      int idx = hist[jj * 2 + par];
      float4 v = *reinterpret_cast<const float4*>(
          &mh_emb[((size_t)f * VOCAB + idx) * EMB + d4]);
      ms.x += v.x; ms.y += v.y; ms.z += v.z; ms.w += v.w;
    }
    ms.x += __shfl_xor(ms.x, 8);
    ms.y += __shfl_xor(ms.y, 8);
    ms.z += __shfl_xor(ms.z, 8);
    ms.w += __shfl_xor(ms.w, 8);
    if (par == 0)
      *reinterpret_cast<float4*>(&L[320 + f * 32 + (sub & 7) * 4]) = ms;
  }

  if (lane < 56) {
    float4 a = *reinterpret_cast<float4*>(&L[lane * 8]);
    float4 b = *reinterpret_cast<float4*>(&L[lane * 8 + 4]);
    bf16x8 o;
    o[0] = (bf16_t)a.x; o[1] = (bf16_t)a.y; o[2] = (bf16_t)a.z; o[3] = (bf16_t)a.w;
    o[4] = (bf16_t)b.x; o[5] = (bf16_t)b.y; o[6] = (bf16_t)b.z; o[7] = (bf16_t)b.w;
    *reinterpret_cast<bf16x8*>(x0b + (size_t)row * IN_DIM + lane * 8) = o;
  }

  float x0v[7], xiv[7];
#pragma unroll
  for (int r = 0; r < 7; ++r) {
    x0v[r] = L[lane + r * 64];
    xiv[r] = x0v[r];
  }
  for (int l = 0; l < CROSS_ORDER; ++l) {
    const float* w = cw + l * IN_DIM;
    const float* b = cb + l * IN_DIM;
    float dot = 0.f;
#pragma unroll
    for (int r = 0; r < 7; ++r) dot += xiv[r] * w[lane + r * 64];
#pragma unroll
    for (int s = 32; s > 0; s >>= 1) dot += __shfl_xor(dot, s);
#pragma unroll
    for (int r = 0; r < 7; ++r) xiv[r] = x0v[r] * dot + b[lane + r * 64] + xiv[r];
  }

  float s = 0.f;
#pragma unroll
  for (int r = 0; r < 7; ++r) s += xiv[r] * lw[lane + r * 64];
#pragma unroll
  for (int t = 32; t > 0; t >>= 1) s += __shfl_xor(s, t);
  if (lane == 0) partial[row] = s;
}

// ---- GEMM1: 256x256 tile, BK=64, 512 threads (8 waves 2Mx4N), 2-slot dbuf,
// counted vmcnt + raw barriers. C = relu(A@Bt^T + bias).
template <int N, int K, int GX>
__global__ __launch_bounds__(512) void gemm_256_db_kernel(
    const bf16_t* __restrict__ A, const bf16_t* __restrict__ Bt,
    const float* __restrict__ bias, bf16_t* __restrict__ C) {
  __shared__ bf16_t As[2][256 * 64];   // 2 x 32 KB
  __shared__ bf16_t Bs[2][256 * 64];   // 2 x 32 KB  -> 128 KB total
  const int tid = threadIdx.x;         // 0..511
  const int lane = tid & 63;
  const int wid = tid >> 6;            // 0..7
  const int wm = wid >> 2;             // 0..1  (M half)
  const int wn = wid & 3;              // 0..3  (N quarter)
  const int nwg = gridDim.x;
  const int bid = blockIdx.x;
  const int swz = (bid & 7) * (nwg >> 3) + (bid >> 3);
  const int row0 = (swz / GX) * 256;
  const int col0 = (swz % GX) * 256;
  constexpr size_t Kb = (size_t)K * 2;
  constexpr int NT = K / 64;           // 7 for K=448

  const int l31 = lane & 31;
  const int lh = lane >> 5;
  const int strow = tid >> 3;          // 0..63 (row within 8KB chunk)
  const int stkb0 = (tid & 7) * 16;    // byte within 128B row

  f32x16 acc[4][2];
#pragma unroll
  for (int m = 0; m < 4; ++m)
#pragma unroll
    for (int n = 0; n < 2; ++n)
#pragma unroll
      for (int r = 0; r < 16; ++r) acc[m][n][r] = 0.f;

  auto STAGE = [&](int slot, int t) {
#pragma unroll
    for (int c = 0; c < 4; ++c) {
      int trow = c * 64 + strow;
      int skb = stkb0 ^ ((trow & 7) << 4);   // pre-swizzled source (rule #21)
      const char* gA = (const char*)A + (size_t)(row0 + trow) * Kb + (size_t)t * 128 + skb;
      const char* gB = (const char*)Bt + (size_t)(col0 + trow) * Kb + (size_t)t * 128 + skb;
      __builtin_amdgcn_global_load_lds((cgvoid*)gA,
          (lvoid*)((char*)As + slot * 32768 + c * 8192 + tid * 16), 16, 0, 0);
      __builtin_amdgcn_global_load_lds((cgvoid*)gB,
          (lvoid*)((char*)Bs + slot * 32768 + c * 8192 + tid * 16), 16, 0, 0);
    }
  };

  STAGE(0, 0);
  for (int t = 0; t < NT; ++t) {
    const int s = t & 1;
    if (t + 1 < NT) {
      STAGE(1 - s, t + 1);                              // next tile into free slot
      asm volatile("s_waitcnt vmcnt(8)" ::: "memory");  // tile t landed; t+1 in flight
    } else {
      asm volatile("s_waitcnt vmcnt(0)" ::: "memory");
    }
    __builtin_amdgcn_s_barrier();   // all waves: tile t ready
    const char* AsS = (const char*)As + s * 32768;
    const char* BsS = (const char*)Bs + s * 32768;
#pragma unroll
    for (int kh = 0; kh < 4; ++kh) {
      const int koff = kh * 32 + lh * 16;
      bf16x8 a[4], b[2];
#pragma unroll
      for (int m = 0; m < 4; ++m) {
        int r = wm * 128 + m * 32 + l31;
        a[m] = *reinterpret_cast<const bf16x8*>(AsS + r * 128 + (koff ^ ((r & 7) << 4)));
      }
#pragma unroll
      for (int n = 0; n < 2; ++n) {
        int cc = wn * 64 + n * 32 + l31;
        b[n] = *reinterpret_cast<const bf16x8*>(BsS + cc * 128 + (koff ^ ((cc & 7) << 4)));
      }
#pragma unroll
      for (int m = 0; m < 4; ++m)
#pragma unroll
        for (int n = 0; n < 2; ++n)
          acc[m][n] = __builtin_amdgcn_mfma_f32_32x32x16_bf16(a[m], b[n], acc[m][n], 0, 0, 0);
    }
    __builtin_amdgcn_s_barrier();   // all reads of slot s done -> overwrite allowed
  }

  // epilogue: 32x32 C/D layout col=lane&31, row=(reg&3)+8*(reg>>2)+4*(lane>>5)
#pragma unroll
  for (int n = 0; n < 2; ++n) {
    int col = col0 + wn * 64 + n * 32 + l31;
    float bv = bias[col];
#pragma unroll
    for (int m = 0; m < 4; ++m) {
#pragma unroll
      for (int r = 0; r < 16; ++r) {
        int row = row0 + wm * 128 + m * 32 + (r & 3) + 8 * (r >> 2) + 4 * lh;
        float v = fmaxf(acc[m][n][r] + bv, 0.f);
        C[(size_t)row * N + col] = (bf16_t)v;
      }
    }
  }
}

// ---- GEMM2: 128x128 tile, BK=64, 2-slot dbuf + counted vmcnt ----
template <int N, int K, int GX>
__global__ __launch_bounds__(256) void gemm_128_db_kernel(
    const bf16_t* __restrict__ A, const bf16_t* __restrict__ Bt,
    const float* __restrict__ bias, bf16_t* __restrict__ C) {
  __shared__ bf16_t As[2][128 * 64];   // 2 x 16 KB
  __shared__ bf16_t Bs[2][128 * 64];   // 2 x 16 KB -> 64 KB total
  const int tid = threadIdx.x;
  const int lane = tid & 63;
  const int wid = tid >> 6;
  const int wr = wid >> 1;
  const int wc = wid & 1;

  const int nwg = gridDim.x;
  const int bid = blockIdx.x;
  const int swz = (bid & 7) * (nwg >> 3) + (bid >> 3);
  const int row0 = (swz / GX) * 128;
  const int col0 = (swz % GX) * 128;
  constexpr size_t Kb = (size_t)K * 2;
  constexpr int NT = K / 64;           // 16 for K=1024

  const int l31 = lane & 31;
  const int lh = lane >> 5;
  const int strow = tid >> 3;          // 0..31 (row within 4KB chunk)
  const int stkb0 = (tid * 16) & 127;  // byte within 128B row

  f32x16 acc[2][2];
#pragma unroll
  for (int m = 0; m < 2; ++m)
#pragma unroll
    for (int n = 0; n < 2; ++n)
#pragma unroll
      for (int r = 0; r < 16; ++r) acc[m][n][r] = 0.f;

  auto STAGE = [&](int slot, int t) {
#pragma unroll
    for (int c = 0; c < 4; ++c) {
      int trow = c * 32 + strow;
      int skb = stkb0 ^ ((trow & 7) << 4);   // pre-swizzled source (rule #21)
      const char* gA = (const char*)A + (size_t)(row0 + trow) * Kb + (size_t)t * 128 + skb;
      const char* gB = (const char*)Bt + (size_t)(col0 + trow) * Kb + (size_t)t * 128 + skb;
      __builtin_amdgcn_global_load_lds((cgvoid*)gA,
          (lvoid*)((char*)As + slot * 16384 + c * 4096 + wid * 1024), 16, 0, 0);
      __builtin_amdgcn_global_load_lds((cgvoid*)gB,
          (lvoid*)((char*)Bs + slot * 16384 + c * 4096 + wid * 1024), 16, 0, 0);
    }
  };

  STAGE(0, 0);
  for (int t = 0; t < NT; ++t) {
    const int s = t & 1;
    if (t + 1 < NT) {
      STAGE(1 - s, t + 1);
      asm volatile("s_waitcnt vmcnt(8)" ::: "memory");
    } else {
      asm volatile("s_waitcnt vmcnt(0)" ::: "memory");
    }
    __builtin_amdgcn_s_barrier();
    const char* AsS = (const char*)As + s * 16384;
    const char* BsS = (const char*)Bs + s * 16384;
#pragma unroll
    for (int kh = 0; kh < 4; ++kh) {
      const int koff = kh * 32 + lh * 16;
      bf16x8 a[2], b[2];
#pragma unroll
      for (int m = 0; m < 2; ++m) {
        int r = wr * 64 + m * 32 + l31;
        a[m] = *reinterpret_cast<const bf16x8*>(AsS + r * 128 + (koff ^ ((r & 7) << 4)));
      }
#pragma unroll
      for (int n = 0; n < 2; ++n) {
        int ccol = wc * 64 + n * 32 + l31;
        b[n] = *reinterpret_cast<const bf16x8*>(BsS + ccol * 128 + (koff ^ ((ccol & 7) << 4)));
      }
#pragma unroll
      for (int m = 0; m < 2; ++m)
#pragma unroll
        for (int n = 0; n < 2; ++n)
          acc[m][n] = __builtin_amdgcn_mfma_f32_32x32x16_bf16(a[m], b[n], acc[m][n], 0, 0, 0);
    }
    __builtin_amdgcn_s_barrier();
  }

#pragma unroll
  for (int n = 0; n < 2; ++n) {
    int col = col0 + wc * 64 + n * 32 + l31;
    float bv = bias[col];
#pragma unroll
    for (int m = 0; m < 2; ++m) {
#pragma unroll
      for (int r = 0; r < 16; ++r) {
        int row = row0 + wr * 64 + m * 32 + (r & 3) + 8 * (r >> 2) + 4 * lh;
        float v = fmaxf(acc[m][n][r] + bv, 0.f);
        C[(size_t)row * N + col] = (bf16_t)v;
      }
    }
  }
}

// ---- fused GEMM3 + head with 2-slot dbuf + counted vmcnt + raw barriers ----
__global__ __launch_bounds__(256) void gemm3_final_kernel(
    const bf16_t* __restrict__ A,      // h2b [B][512]
    const bf16_t* __restrict__ Bt,     // wT3 [256][512]
    const float* __restrict__ bias,    // b3
    const float* __restrict__ lw,      // lin_w [704]
    const float* __restrict__ lb,      // lin_b
    const float* __restrict__ partial, // [B]
    float* __restrict__ out) {
  constexpr int K = HID2;  // 512
  __shared__ bf16_t As[2][64 * 64];     // 2 x 8 KB
  __shared__ bf16_t Bs[2][256 * 64];    // 2 x 32 KB -> 80 KB total
  __shared__ float rowsum[64][2];
  const int tid = threadIdx.x;
  const int lane = tid & 63;
  const int wid = tid >> 6;
  const int wr = wid >> 1;
  const int wc = wid & 1;
  const int nwg = gridDim.x;
  const int bid = blockIdx.x;
  const int swz = (bid & 7) * (nwg >> 3) + (bid >> 3);
  const int row0 = swz * 64;
  constexpr size_t Kb = (size_t)K * 2;
  constexpr int NT = K / 64;            // 8

  const int l31 = lane & 31;
  const int lh = lane >> 5;
  const int strow = tid >> 3;
  const int stkb0 = (tid * 16) & 127;

  f32x16 acc[4];
#pragma unroll
  for (int n = 0; n < 4; ++n)
#pragma unroll
    for (int r = 0; r < 16; ++r) acc[n][r] = 0.f;

  auto STAGE = [&](int slot, int t) {
#pragma unroll
    for (int c = 0; c < 2; ++c) {
      int trow = c * 32 + strow;
      int skb = stkb0 ^ ((trow & 7) << 4);
      const char* gA = (const char*)A + (size_t)(row0 + trow) * Kb + (size_t)t * 128 + skb;
      __builtin_amdgcn_global_load_lds((cgvoid*)gA,
          (lvoid*)((char*)As + slot * 8192 + c * 4096 + wid * 1024), 16, 0, 0);
    }
#pragma unroll
    for (int c = 0; c < 8; ++c) {
      int trow = c * 32 + strow;
      int skb = stkb0 ^ ((trow & 7) << 4);
      const char* gB = (const char*)Bt + (size_t)trow * Kb + (size_t)t * 128 + skb;
      __builtin_amdgcn_global_load_lds((cgvoid*)gB,
          (lvoid*)((char*)Bs + slot * 32768 + c * 4096 + wid * 1024), 16, 0, 0);
    }
  };

  STAGE(0, 0);
  for (int t = 0; t < NT; ++t) {
    const int s = t & 1;
    if (t + 1 < NT) {
      STAGE(1 - s, t + 1);
      asm volatile("s_waitcnt vmcnt(10)" ::: "memory");
    } else {
      asm volatile("s_waitcnt vmcnt(0)" ::: "memory");
    }
    __builtin_amdgcn_s_barrier();
    const char* AsS = (const char*)As + s * 8192;
    const char* BsS = (const char*)Bs + s * 32768;
#pragma unroll
    for (int kh = 0; kh < 4; ++kh) {
      const int koff = kh * 32 + lh * 16;
      int ar = wr * 32 + l31;
      bf16x8 a = *reinterpret_cast<const bf16x8*>(
          AsS + ar * 128 + (koff ^ ((ar & 7) << 4)));
      bf16x8 b[4];
#pragma unroll
      for (int n = 0; n < 4; ++n) {
        int bc = wc * 128 + n * 32 + l31;
        b[n] = *reinterpret_cast<const bf16x8*>(
            BsS + bc * 128 + (koff ^ ((bc & 7) << 4)));
      }
#pragma unroll
      for (int n = 0; n < 4; ++n)
        acc[n] = __builtin_amdgcn_mfma_f32_32x32x16_bf16(a, b[n], acc[n], 0, 0, 0);
    }
    __builtin_amdgcn_s_barrier();
  }

  // head epilogue
  float bv[4], wv[4];
#pragma unroll
  for (int n = 0; n < 4; ++n) {
    int col = wc * 128 + n * 32 + l31;
    bv[n] = bias[col];
    wv[n] = lw[IN_DIM + col];
  }
#pragma unroll
  for (int r = 0; r < 16; ++r) {
    float v = 0.f;
#pragma unroll
    for (int n = 0; n < 4; ++n) {
      float h = fmaxf(acc[n][r] + bv[n], 0.f);
      v += h * wv[n];
    }
#pragma unroll
    for (int t = 16; t > 0; t >>= 1) v += __shfl_xor(v, t);
    if (l31 == 0)
      rowsum[wr * 32 + (r & 3) + 8 * (r >> 2) + 4 * lh][wc] = v;
  }
  __syncthreads();
  if (tid < 64) {
    int grow = row0 + tid;
    float s = rowsum[tid][0] + rowsum[tid][1] + partial[grow] + lb[0];
    out[grow] = 1.f / (1.f + expf(-s));
  }
}

extern "C" void kernel_launch(void* const* d_in, const int* in_sizes, int n_in,
                              void* d_out, int out_size, void* d_ws, size_t ws_size,
                              hipStream_t stream) {
  const float* dense = (const float*)d_in[0];
  const int* oh_idx = (const int*)d_in[1];
  const int* mh_idx = (const int*)d_in[2];
  const float* oh_emb = (const float*)d_in[3];
  const float* mh_emb = (const float*)d_in[4];
  const float* cw = (const float*)d_in[5];
  const float* cb = (const float*)d_in[6];
  const float* W1 = (const float*)d_in[7];
  const float* b1 = (const float*)d_in[8];
  const float* W2 = (const float*)d_in[9];
  const float* b2 = (const float*)d_in[10];
  const float* W3 = (const float*)d_in[11];
  const float* b3 = (const float*)d_in[12];
  const float* lw = (const float*)d_in[13];
  const float* lb = (const float*)d_in[14];
  float* out = (float*)d_out;

  // workspace layout (~68 MB)
  char* p = (char*)d_ws;
  bf16_t* x0b = (bf16_t*)p;  p += (size_t)B_SZ * IN_DIM * 2;
  bf16_t* h1b = (bf16_t*)p;  p += (size_t)B_SZ * HID1 * 2;
  bf16_t* h2b = (bf16_t*)p;  p += (size_t)B_SZ * HID2 * 2;
  bf16_t* wT1 = (bf16_t*)p;  p += (size_t)HID1 * IN_DIM * 2;
  bf16_t* wT2 = (bf16_t*)p;  p += (size_t)HID2 * HID1 * 2;
  bf16_t* wT3 = (bf16_t*)p;  p += (size_t)HID2 * HID3 * 2;
  float* partial = (float*)p; p += (size_t)B_SZ * 4;

  embed_cross_transpose_kernel<<<TRT_BLOCKS + EMB_BLOCKS, 256, 0, stream>>>(
      dense, oh_idx, mh_idx, oh_emb, mh_emb, cw, cb, lw,
      W1, W2, W3, wT1, wT2, wT3, x0b, partial);

  // G1: 256^2 dbuf pipeline, 256 blocks (1/CU)
  gemm_256_db_kernel<HID1, IN_DIM, HID1 / 256>
      <<<(B_SZ / 256) * (HID1 / 256), 512, 0, stream>>>(x0b, wT1, b1, h1b);
  // G2: 128^2 dbuf pipeline, 512 blocks (2/CU)
  gemm_128_db_kernel<HID2, HID1, HID2 / 128>
      <<<(B_SZ / 128) * (HID2 / 128), 256, 0, stream>>>(h1b, wT2, b2, h2b);

  gemm3_final_kernel<<<B_SZ / 64, 256, 0, stream>>>(
      h2b, wT3, b3, lw, lb, partial, out);
}